// Round 1
// baseline (979.749 us; speedup 1.0000x reference)
//
#include <hip/hip_runtime.h>

#define NPREF 32
#define DIM   64

__global__ __launch_bounds__(256, 2) void transup_score_kernel(
    const int*   __restrict__ u_ids,
    const int*   __restrict__ i_ids,
    const float* __restrict__ user_w,
    const float* __restrict__ item_w,
    const float* __restrict__ pref_w,   // [NPREF][DIM], wave-uniform reads -> s_load
    const float* __restrict__ norm_w,   // [NPREF][DIM]
    float*       __restrict__ out,
    int n)
{
    const int e = blockIdx.x * blockDim.x + threadIdx.x;
    if (e >= n) return;

    const long uid = u_ids[e];
    const long iid = i_ids[e];

    const float4* __restrict__ up = reinterpret_cast<const float4*>(user_w + uid * DIM);
    const float4* __restrict__ ip = reinterpret_cast<const float4*>(item_w + iid * DIM);

    // Issue both row gathers fully vectorized; 32 VMEM loads in flight.
    float4 uv[DIM / 4];
    float4 iv[DIM / 4];
#pragma unroll
    for (int k = 0; k < DIM / 4; ++k) uv[k] = up[k];
#pragma unroll
    for (int k = 0; k < DIM / 4; ++k) iv[k] = ip[k];

    // s = u + i (phase-1 only), df = u - i (lives to the end)
    float s[DIM], df[DIM];
#pragma unroll
    for (int k = 0; k < DIM / 4; ++k) {
        s[4 * k + 0] = uv[k].x + iv[k].x;  df[4 * k + 0] = uv[k].x - iv[k].x;
        s[4 * k + 1] = uv[k].y + iv[k].y;  df[4 * k + 1] = uv[k].y - iv[k].y;
        s[4 * k + 2] = uv[k].z + iv[k].z;  df[4 * k + 2] = uv[k].z - iv[k].z;
        s[4 * k + 3] = uv[k].w + iv[k].w;  df[4 * k + 3] = uv[k].w - iv[k].w;
    }

    // Phase 1: pre[p] = 0.5 * <s, P[p]>   (P read via uniform address -> SGPR operand)
    float pre[NPREF];
#pragma unroll
    for (int p = 0; p < NPREF; ++p) {
        float acc = 0.f;
#pragma unroll
        for (int d = 0; d < DIM; ++d) acc += s[d] * pref_w[p * DIM + d];
        pre[p] = 0.5f * acc;
    }

    // Phase 2a: nrm = pre @ N
    float nrm[DIM];
#pragma unroll
    for (int d = 0; d < DIM; ++d) nrm[d] = 0.f;
#pragma unroll
    for (int p = 0; p < NPREF; ++p) {
        const float pp = pre[p];
#pragma unroll
        for (int d = 0; d < DIM; ++d) nrm[d] += pp * norm_w[p * DIM + d];
    }

    // dot = <df, nrm>   (note: (u.n)n - (i.n)n == ((u-i).n) n)
    float dot = 0.f;
#pragma unroll
    for (int d = 0; d < DIM; ++d) dot += df[d] * nrm[d];

    // Phase 2b: df += pre @ P  (r_e accumulated in place; s is dead, regs reused)
#pragma unroll
    for (int p = 0; p < NPREF; ++p) {
        const float pp = pre[p];
#pragma unroll
        for (int d = 0; d < DIM; ++d) df[d] += pp * pref_w[p * DIM + d];
    }

    // out = sum_d | df + r_e - dot*nrm |
    float o = 0.f;
#pragma unroll
    for (int d = 0; d < DIM; ++d) o += fabsf(df[d] - dot * nrm[d]);

    out[e] = o;
}

extern "C" void kernel_launch(void* const* d_in, const int* in_sizes, int n_in,
                              void* d_out, int out_size, void* d_ws, size_t ws_size,
                              hipStream_t stream) {
    const int*   u_ids  = (const int*)d_in[0];
    const int*   i_ids  = (const int*)d_in[1];
    const float* user_w = (const float*)d_in[2];
    const float* item_w = (const float*)d_in[3];
    const float* pref_w = (const float*)d_in[4];
    const float* norm_w = (const float*)d_in[5];
    float*       out    = (float*)d_out;

    const int n     = in_sizes[0];
    const int block = 256;
    const int grid  = (n + block - 1) / block;

    transup_score_kernel<<<grid, block, 0, stream>>>(
        u_ids, i_ids, user_w, item_w, pref_w, norm_w, out, n);
}

// Round 2
// 721.425 us; speedup vs baseline: 1.3581x; 1.3581x over previous
//
#include <hip/hip_runtime.h>

#define NPREF 32
#define DIM   64
#define SUBD  16                 // dims owned by each lane of a quad
#define QPB   64                 // quads (elements) per 256-thread block

// 4-lane butterfly pieces via ds_swizzle (no address VGPR needed).
// BitMode offset = (xor<<10) | (or<<5) | and(0x1F)
__device__ __forceinline__ float swz_xor1(float x) {
    return __int_as_float(__builtin_amdgcn_ds_swizzle(__float_as_int(x), 0x041F));
}
__device__ __forceinline__ float swz_xor2(float x) {
    return __int_as_float(__builtin_amdgcn_ds_swizzle(__float_as_int(x), 0x081F));
}
__device__ __forceinline__ float quad_sum(float x) {
    x += swz_xor1(x);
    x += swz_xor2(x);
    return x;
}

__global__ __launch_bounds__(256, 3) void transup_score_kernel(
    const int*   __restrict__ u_ids,
    const int*   __restrict__ i_ids,
    const float* __restrict__ user_w,
    const float* __restrict__ item_w,
    const float* __restrict__ pref_w,
    const float* __restrict__ norm_w,
    float*       __restrict__ out,
    int n)
{
    __shared__ float4 ldsP[NPREF * DIM / 4];   // 8 KB
    __shared__ float4 ldsN[NPREF * DIM / 4];   // 8 KB

    // Stage both expert matrices into LDS (L2-resident after first blocks).
    {
        const float4* Pg = reinterpret_cast<const float4*>(pref_w);
        const float4* Ng = reinterpret_cast<const float4*>(norm_w);
        for (int k = threadIdx.x; k < NPREF * DIM / 4; k += 256) {
            ldsP[k] = Pg[k];
            ldsN[k] = Ng[k];
        }
    }
    __syncthreads();

    const int sub = threadIdx.x & 3;           // which 16-dim slice of the element
    const int e   = blockIdx.x * QPB + (threadIdx.x >> 2);
    if (e >= n) return;

    const size_t uid = (size_t)u_ids[e];
    const size_t iid = (size_t)i_ids[e];

    // Gather this lane's 64B slice of each row: quad covers 256B contiguous.
    const float4* up = reinterpret_cast<const float4*>(user_w + uid * DIM) + sub * 4;
    const float4* ip = reinterpret_cast<const float4*>(item_w + iid * DIM) + sub * 4;

    alignas(16) float uu[SUBD], vv[SUBD];
    {
        float4 a0 = up[0], a1 = up[1], a2 = up[2], a3 = up[3];
        float4 b0 = ip[0], b1 = ip[1], b2 = ip[2], b3 = ip[3];
        reinterpret_cast<float4*>(uu)[0] = a0; reinterpret_cast<float4*>(uu)[1] = a1;
        reinterpret_cast<float4*>(uu)[2] = a2; reinterpret_cast<float4*>(uu)[3] = a3;
        reinterpret_cast<float4*>(vv)[0] = b0; reinterpret_cast<float4*>(vv)[1] = b1;
        reinterpret_cast<float4*>(vv)[2] = b2; reinterpret_cast<float4*>(vv)[3] = b3;
    }

    float s[SUBD], df[SUBD], re[SUBD], nm[SUBD];
#pragma unroll
    for (int d = 0; d < SUBD; ++d) {
        s[d]  = 0.5f * (uu[d] + vv[d]);   // fold the 0.5 routing scale into s
        df[d] = uu[d] - vv[d];
        re[d] = 0.f;
        nm[d] = 0.f;
    }

    const float4* Prow = ldsP + sub * 4;   // expert p chunk at Prow[p*16 + 0..3]
    const float4* Nrow = ldsN + sub * 4;

    // Single fused pass over experts, 4 at a time (batch the swizzle latency).
#pragma unroll
    for (int g = 0; g < NPREF / 4; ++g) {
        float a[4];
#pragma unroll
        for (int j = 0; j < 4; ++j) {
            const int p = g * 4 + j;
            alignas(16) float pv[SUBD];
            reinterpret_cast<float4*>(pv)[0] = Prow[p * 16 + 0];
            reinterpret_cast<float4*>(pv)[1] = Prow[p * 16 + 1];
            reinterpret_cast<float4*>(pv)[2] = Prow[p * 16 + 2];
            reinterpret_cast<float4*>(pv)[3] = Prow[p * 16 + 3];
            // 4 independent partial chains for ILP
            float c0 = 0.f, c1 = 0.f, c2 = 0.f, c3 = 0.f;
#pragma unroll
            for (int q = 0; q < 4; ++q) {
                c0 += s[4 * q + 0] * pv[4 * q + 0];
                c1 += s[4 * q + 1] * pv[4 * q + 1];
                c2 += s[4 * q + 2] * pv[4 * q + 2];
                c3 += s[4 * q + 3] * pv[4 * q + 3];
            }
            a[j] = (c0 + c1) + (c2 + c3);
        }
        // Batched 4-lane reduction -> every lane holds pre[p] for these 4 experts.
#pragma unroll
        for (int j = 0; j < 4; ++j) a[j] += swz_xor1(a[j]);
#pragma unroll
        for (int j = 0; j < 4; ++j) a[j] += swz_xor2(a[j]);

#pragma unroll
        for (int j = 0; j < 4; ++j) {
            const int p = g * 4 + j;
            alignas(16) float pv[SUBD], nv[SUBD];
            reinterpret_cast<float4*>(pv)[0] = Prow[p * 16 + 0];
            reinterpret_cast<float4*>(pv)[1] = Prow[p * 16 + 1];
            reinterpret_cast<float4*>(pv)[2] = Prow[p * 16 + 2];
            reinterpret_cast<float4*>(pv)[3] = Prow[p * 16 + 3];
            reinterpret_cast<float4*>(nv)[0] = Nrow[p * 16 + 0];
            reinterpret_cast<float4*>(nv)[1] = Nrow[p * 16 + 1];
            reinterpret_cast<float4*>(nv)[2] = Nrow[p * 16 + 2];
            reinterpret_cast<float4*>(nv)[3] = Nrow[p * 16 + 3];
            const float pp = a[j];
#pragma unroll
            for (int d = 0; d < SUBD; ++d) {
                re[d] += pp * pv[d];
                nm[d] += pp * nv[d];
            }
        }
    }

    // dot = <u-i, norm> across the full 64 dims
    float c0 = 0.f, c1 = 0.f, c2 = 0.f, c3 = 0.f;
#pragma unroll
    for (int q = 0; q < 4; ++q) {
        c0 += df[4 * q + 0] * nm[4 * q + 0];
        c1 += df[4 * q + 1] * nm[4 * q + 1];
        c2 += df[4 * q + 2] * nm[4 * q + 2];
        c3 += df[4 * q + 3] * nm[4 * q + 3];
    }
    float dot = quad_sum((c0 + c1) + (c2 + c3));

    // out = sum_d | (u-i) + r_e - dot * norm |
    float o0 = 0.f, o1 = 0.f, o2 = 0.f, o3 = 0.f;
#pragma unroll
    for (int q = 0; q < 4; ++q) {
        o0 += fabsf(fmaf(-dot, nm[4 * q + 0], df[4 * q + 0] + re[4 * q + 0]));
        o1 += fabsf(fmaf(-dot, nm[4 * q + 1], df[4 * q + 1] + re[4 * q + 1]));
        o2 += fabsf(fmaf(-dot, nm[4 * q + 2], df[4 * q + 2] + re[4 * q + 2]));
        o3 += fabsf(fmaf(-dot, nm[4 * q + 3], df[4 * q + 3] + re[4 * q + 3]));
    }
    float o = quad_sum((o0 + o1) + (o2 + o3));

    if (sub == 0) out[e] = o;
}

extern "C" void kernel_launch(void* const* d_in, const int* in_sizes, int n_in,
                              void* d_out, int out_size, void* d_ws, size_t ws_size,
                              hipStream_t stream) {
    const int*   u_ids  = (const int*)d_in[0];
    const int*   i_ids  = (const int*)d_in[1];
    const float* user_w = (const float*)d_in[2];
    const float* item_w = (const float*)d_in[3];
    const float* pref_w = (const float*)d_in[4];
    const float* norm_w = (const float*)d_in[5];
    float*       out    = (float*)d_out;

    const int n    = in_sizes[0];
    const int grid = (n + QPB - 1) / QPB;

    transup_score_kernel<<<grid, 256, 0, stream>>>(
        u_ids, i_ids, user_w, item_w, pref_w, norm_w, out, n);
}